// Round 7
// baseline (317.189 us; speedup 1.0000x reference)
//
#include <hip/hip_runtime.h>
#include <hip/hip_bf16.h>

// B=128, T=512, D_IN=512, D_OUT=512
// currents[M=65536][512] = X . W^T + b (bf16 MFMA, bf16 currents in d_ws),
// then LIF scan over T -> f32 spikes in d_out + exact spike-count sum.
#define M_TOT 65536
#define K_DIM 512
#define N_DIM 512
#define T_STEPS 512
#define BETA 0.95f

#define BM 128
#define BN 128
#define BK 64

typedef __attribute__((ext_vector_type(8))) short bf16x8;
typedef __attribute__((ext_vector_type(8))) unsigned short u16x8;
typedef __attribute__((ext_vector_type(4))) float f32x4;

#define X_ELEMS ((size_t)M_TOT * K_DIM)   // 33,554,432
#define W_ELEMS ((size_t)N_DIM * K_DIM)   // 262,144
// ws layout: Xb | Wb | Cb  (all bf16)
#define WS_NEEDED ((X_ELEMS + W_ELEMS + X_ELEMS) * 2)

static __device__ __forceinline__ unsigned short f2bf(float f) {
    __hip_bfloat16 h = __float2bfloat16(f);   // v_cvt_pk_bf16_f32 (RNE)
    return __builtin_bit_cast(unsigned short, h);
}
static __device__ __forceinline__ float bf2f(unsigned short u) {
    return __builtin_bit_cast(float, (unsigned int)u << 16);
}

// ---------------- pass 1: f32 -> bf16 for X and W, zero the sum slot ----------
__global__ __launch_bounds__(256) void convert_bf16(
    const float* __restrict__ X, const float* __restrict__ W,
    unsigned short* __restrict__ Xb, unsigned short* __restrict__ Wb,
    float* __restrict__ sum_out)
{
    const size_t gid = (size_t)blockIdx.x * 256 + threadIdx.x;
    if (gid == 0) *sum_out = 0.0f;
    const size_t NXT = X_ELEMS / 8;
    if (gid < NXT) {
        const float4 v0 = *(const float4*)(X + gid * 8);
        const float4 v1 = *(const float4*)(X + gid * 8 + 4);
        u16x8 o;
        o[0] = f2bf(v0.x); o[1] = f2bf(v0.y); o[2] = f2bf(v0.z); o[3] = f2bf(v0.w);
        o[4] = f2bf(v1.x); o[5] = f2bf(v1.y); o[6] = f2bf(v1.z); o[7] = f2bf(v1.w);
        *(u16x8*)(Xb + gid * 8) = o;
    } else {
        const size_t g2 = gid - NXT;
        const float4 v0 = *(const float4*)(W + g2 * 8);
        const float4 v1 = *(const float4*)(W + g2 * 8 + 4);
        u16x8 o;
        o[0] = f2bf(v0.x); o[1] = f2bf(v0.y); o[2] = f2bf(v0.z); o[3] = f2bf(v0.w);
        o[4] = f2bf(v1.x); o[5] = f2bf(v1.y); o[6] = f2bf(v1.z); o[7] = f2bf(v1.w);
        *(u16x8*)(Wb + g2 * 8) = o;
    }
}

// ---------------- pass 2: 2-phase double-buffered m97-structure GEMM ----------
// global_load_lds 16B, linear LDS dest, pre-swizzled global source (rule #21);
// STAGE(t+1) issued BEFORE compute(t) so load latency hides under the MFMAs.
__global__ __launch_bounds__(256) void gemm_fast(
    const unsigned short* __restrict__ Xb,  // [M_TOT][K_DIM] bf16
    const unsigned short* __restrict__ Wb,  // [N_DIM][K_DIM] bf16
    const float* __restrict__ bias,
    unsigned short* __restrict__ Cb)        // [M_TOT][N_DIM] bf16 currents
{
    __shared__ alignas(16) unsigned short Xs[2][BM][BK]; // 2 x 16 KB
    __shared__ alignas(16) unsigned short Ws[2][BN][BK]; // 2 x 16 KB

    const int lin  = blockIdx.x;            // 0..2047 (2048 % 8 == 0: bijective)
    const int swz  = (lin & 7) * 256 + (lin >> 3);
    const int mtile = swz >> 2;
    const int ntile = swz & 3;

    const int tid  = threadIdx.x;
    const int lane = tid & 63;
    const int wave = tid >> 6;
    const int wr = wave >> 1;
    const int wc = wave & 1;

    const int row0 = mtile * BM;
    const int col0 = ntile * BN;

    f32x4 acc[4][4] = {};

    // staging: instruction (wave,j) fills LDS rows wave*32+j*8..+7 (1 KB);
    // HW dest = base + lane*16; source pre-swizzled: blk = (lane&7) ^ ((lane>>3)&7)
    const int srow = lane >> 3;
    const int scb  = (lane & 7) ^ (srow & 7);
    const unsigned short* xsrc[4];
    const unsigned short* wsrc[4];
    #pragma unroll
    for (int j = 0; j < 4; ++j) {
        const int ra = row0 + wave * 32 + j * 8 + srow;
        const int rb = col0 + wave * 32 + j * 8 + srow;
        xsrc[j] = Xb + (size_t)ra * K_DIM + scb * 8;
        wsrc[j] = Wb + (size_t)rb * K_DIM + scb * 8;
    }

    const int frow = lane & 15;
    const int cblk = lane >> 4;

    // prologue: stage K-step 0 into buf 0
    #pragma unroll
    for (int j = 0; j < 4; ++j) {
        __builtin_amdgcn_global_load_lds(
            (const __attribute__((address_space(1))) unsigned int*)(const void*)(xsrc[j]),
            (__attribute__((address_space(3))) unsigned int*)(void*)(&Xs[0][wave * 32 + j * 8][0]),
            16, 0, 0);
        __builtin_amdgcn_global_load_lds(
            (const __attribute__((address_space(1))) unsigned int*)(const void*)(wsrc[j]),
            (__attribute__((address_space(3))) unsigned int*)(void*)(&Ws[0][wave * 32 + j * 8][0]),
            16, 0, 0);
    }

    #pragma unroll
    for (int t = 0; t < 8; ++t) {
        const int cur = t & 1;
        __syncthreads();   // drains vmcnt: buf[cur] staged; prev reads of buf[cur^1] done

        // issue next K-step's loads into the other buffer (in flight during MFMAs)
        if (t < 7) {
            #pragma unroll
            for (int j = 0; j < 4; ++j) {
                __builtin_amdgcn_global_load_lds(
                    (const __attribute__((address_space(1))) unsigned int*)(const void*)(xsrc[j] + (t + 1) * BK),
                    (__attribute__((address_space(3))) unsigned int*)(void*)(&Xs[cur ^ 1][wave * 32 + j * 8][0]),
                    16, 0, 0);
                __builtin_amdgcn_global_load_lds(
                    (const __attribute__((address_space(1))) unsigned int*)(const void*)(wsrc[j] + (t + 1) * BK),
                    (__attribute__((address_space(3))) unsigned int*)(void*)(&Ws[cur ^ 1][wave * 32 + j * 8][0]),
                    16, 0, 0);
            }
        }

        // compute from buf[cur]
        #pragma unroll
        for (int kh = 0; kh < 2; ++kh) {
            bf16x8 afr[4], bfr[4];
            #pragma unroll
            for (int m = 0; m < 4; ++m) {
                int row = wr * 64 + m * 16 + frow;
                int c = (kh * 4 + cblk) ^ (row & 7);
                afr[m] = *(const bf16x8*)(&Xs[cur][row][c * 8]);
            }
            #pragma unroll
            for (int n = 0; n < 4; ++n) {
                int row = wc * 64 + n * 16 + frow;
                int c = (kh * 4 + cblk) ^ (row & 7);
                bfr[n] = *(const bf16x8*)(&Ws[cur][row][c * 8]);
            }
            #pragma unroll
            for (int m = 0; m < 4; ++m)
                #pragma unroll
                for (int n = 0; n < 4; ++n)
                    acc[m][n] = __builtin_amdgcn_mfma_f32_16x16x32_bf16(
                        afr[m], bfr[n], acc[m][n], 0, 0, 0);
        }
    }

    // epilogue: C/D layout col=lane&15, row=(lane>>4)*4+reg ; bf16 currents
    const int crow_base = (lane >> 4) * 4;
    const int ccol = lane & 15;
    #pragma unroll
    for (int n = 0; n < 4; ++n) {
        int col = col0 + wc * 64 + n * 16 + ccol;
        float bv = bias[col];
        #pragma unroll
        for (int m = 0; m < 4; ++m) {
            int rowb = row0 + wr * 64 + m * 16 + crow_base;
            #pragma unroll
            for (int r = 0; r < 4; ++r) {
                Cb[(size_t)(rowb + r) * N_DIM + col] = f2bf(acc[m][n][r] + bv);
            }
        }
    }
}

// ---------------- pass 3: LIF scan, bf16 currents in, f32 spikes out ---------
__global__ __launch_bounds__(256) void lif_scan(
    const unsigned short* __restrict__ Cb,  // [B][T][D] bf16 currents
    float* __restrict__ S,                  // [B][T][D] f32 spikes
    float* __restrict__ sum_out)
{
    const int idx = blockIdx.x * 256 + threadIdx.x;  // 0..65535
    const size_t base = (size_t)(idx >> 9) * (T_STEPS * N_DIM) + (idx & 511);
    const unsigned short* p = Cb + base;
    float* q = S + base;

    float mem = 0.0f;
    int count = 0;
    float a[32], b[32];

    #pragma unroll
    for (int j = 0; j < 32; ++j)
        a[j] = bf2f(p[(size_t)j * N_DIM]);

    for (int t = 0; t < T_STEPS; t += 64) {
        #pragma unroll
        for (int j = 0; j < 32; ++j)
            b[j] = bf2f(p[(size_t)(t + 32 + j) * N_DIM]);
        #pragma unroll
        for (int j = 0; j < 32; ++j) {
            mem = BETA * mem + a[j];
            float spk = (mem > 1.0f) ? 1.0f : 0.0f;
            mem -= spk;
            __builtin_nontemporal_store(spk, q + (size_t)(t + j) * N_DIM);
            count += (int)spk;
        }
        if (t + 64 < T_STEPS) {
            #pragma unroll
            for (int j = 0; j < 32; ++j)
                a[j] = bf2f(p[(size_t)(t + 64 + j) * N_DIM]);
        }
        #pragma unroll
        for (int j = 0; j < 32; ++j) {
            mem = BETA * mem + b[j];
            float spk = (mem > 1.0f) ? 1.0f : 0.0f;
            mem -= spk;
            __builtin_nontemporal_store(spk, q + (size_t)(t + 32 + j) * N_DIM);
            count += (int)spk;
        }
    }

    #pragma unroll
    for (int off = 32; off > 0; off >>= 1)
        count += __shfl_down(count, off);
    __shared__ int wsum[4];
    if ((threadIdx.x & 63) == 0) wsum[threadIdx.x >> 6] = count;
    __syncthreads();
    if (threadIdx.x == 0) {
        int tot = wsum[0] + wsum[1] + wsum[2] + wsum[3];
        atomicAdd(sum_out, (float)tot);
    }
}

// ---------------- fallback (ws too small): round-5 f32-staging GEMM ----------
static __device__ __forceinline__ void stage_tiles(
    unsigned short (*__restrict__ Xs)[BK], unsigned short (*__restrict__ Ws)[BK],
    const float4* xr, const float4* wv, int sr0, int skg)
{
    #pragma unroll
    for (int i = 0; i < 8; ++i) {
        int r   = sr0 + i * 16;
        int kgs = skg ^ ((r & 7) << 3);
        ushort4 xb, wb;
        xb.x = f2bf(xr[i].x); xb.y = f2bf(xr[i].y); xb.z = f2bf(xr[i].z); xb.w = f2bf(xr[i].w);
        wb.x = f2bf(wv[i].x); wb.y = f2bf(wv[i].y); wb.z = f2bf(wv[i].z); wb.w = f2bf(wv[i].w);
        *(ushort4*)(&Xs[r][kgs]) = xb;
        *(ushort4*)(&Ws[r][kgs]) = wb;
    }
}

__global__ __launch_bounds__(256, 2) void gemm_slow(
    const float* __restrict__ X, const float* __restrict__ W,
    const float* __restrict__ bias, float* __restrict__ C,
    float* __restrict__ sum_out)
{
    __shared__ unsigned short Xs[2][BM][BK];
    __shared__ unsigned short Ws[2][BN][BK];

    const int lin  = blockIdx.x;
    const int swz  = (lin & 7) * 256 + (lin >> 3);
    const int mtile = swz >> 2;
    const int ntile = swz & 3;

    const int tid  = threadIdx.x;
    const int lane = tid & 63;
    const int wave = tid >> 6;
    const int wr = wave >> 1;
    const int wc = wave & 1;

    if (lin == 0 && tid == 0) *sum_out = 0.0f;

    const int row0 = mtile * BM;
    const int col0 = ntile * BN;

    f32x4 acc[4][4] = {};

    const int sr0 = tid >> 4;
    const int skg = (tid & 15) << 2;
    const float* xbase = X + (size_t)row0 * K_DIM + skg;
    const float* wbase = W + (size_t)col0 * K_DIM + skg;

    float4 xr[8], wv[8];
    #pragma unroll
    for (int i = 0; i < 8; ++i) {
        int r = sr0 + i * 16;
        xr[i] = *(const float4*)(xbase + (size_t)r * K_DIM);
        wv[i] = *(const float4*)(wbase + (size_t)r * K_DIM);
    }
    stage_tiles(Xs[0], Ws[0], xr, wv, sr0, skg);

    const int frow = lane & 15;
    const int cblk = lane >> 4;

    for (int t = 0; t < 8; ++t) {
        __syncthreads();
        if (t < 7) {
            const int k0n = (t + 1) * BK;
            #pragma unroll
            for (int i = 0; i < 8; ++i) {
                int r = sr0 + i * 16;
                xr[i] = *(const float4*)(xbase + (size_t)r * K_DIM + k0n);
                wv[i] = *(const float4*)(wbase + (size_t)r * K_DIM + k0n);
            }
        }
        unsigned short (*Xbuf)[BK] = Xs[t & 1];
        unsigned short (*Wbuf)[BK] = Ws[t & 1];
        #pragma unroll
        for (int kh = 0; kh < 2; ++kh) {
            bf16x8 afr[4], bfr[4];
            #pragma unroll
            for (int m = 0; m < 4; ++m) {
                int row = wr * 64 + m * 16 + frow;
                int c = (kh * 4 + cblk) ^ (row & 7);
                afr[m] = *(const bf16x8*)(&Xbuf[row][c * 8]);
            }
            #pragma unroll
            for (int n = 0; n < 4; ++n) {
                int row = wc * 64 + n * 16 + frow;
                int c = (kh * 4 + cblk) ^ (row & 7);
                bfr[n] = *(const bf16x8*)(&Wbuf[row][c * 8]);
            }
            #pragma unroll
            for (int m = 0; m < 4; ++m)
                #pragma unroll
                for (int n = 0; n < 4; ++n)
                    acc[m][n] = __builtin_amdgcn_mfma_f32_16x16x32_bf16(
                        afr[m], bfr[n], acc[m][n], 0, 0, 0);
        }
        if (t < 7)
            stage_tiles(Xs[(t + 1) & 1], Ws[(t + 1) & 1], xr, wv, sr0, skg);
    }

    const int crow_base = (lane >> 4) * 4;
    const int ccol = lane & 15;
    #pragma unroll
    for (int n = 0; n < 4; ++n) {
        int col = col0 + wc * 64 + n * 16 + ccol;
        float bv = bias[col];
        #pragma unroll
        for (int m = 0; m < 4; ++m) {
            int rowb = row0 + wr * 64 + m * 16 + crow_base;
            #pragma unroll
            for (int r = 0; r < 4; ++r) {
                C[(size_t)(rowb + r) * N_DIM + col] = acc[m][n][r] + bv;
            }
        }
    }
}

__global__ __launch_bounds__(256) void lif_scan_f32(
    float* __restrict__ C, float* __restrict__ sum_out)
{
    const int idx = blockIdx.x * 256 + threadIdx.x;
    float* p = C + (size_t)(idx >> 9) * (T_STEPS * N_DIM) + (idx & 511);
    float mem = 0.0f;
    int count = 0;
    for (int t = 0; t < T_STEPS; t += 8) {
        float cur[8];
        #pragma unroll
        for (int j = 0; j < 8; ++j) cur[j] = p[(size_t)(t + j) * N_DIM];
        #pragma unroll
        for (int j = 0; j < 8; ++j) {
            mem = BETA * mem + cur[j];
            float spk = (mem > 1.0f) ? 1.0f : 0.0f;
            mem -= spk;
            p[(size_t)(t + j) * N_DIM] = spk;
            count += (int)spk;
        }
    }
    #pragma unroll
    for (int off = 32; off > 0; off >>= 1) count += __shfl_down(count, off);
    __shared__ int wsum[4];
    if ((threadIdx.x & 63) == 0) wsum[threadIdx.x >> 6] = count;
    __syncthreads();
    if (threadIdx.x == 0)
        atomicAdd(sum_out, (float)(wsum[0] + wsum[1] + wsum[2] + wsum[3]));
}

extern "C" void kernel_launch(void* const* d_in, const int* in_sizes, int n_in,
                              void* d_out, int out_size, void* d_ws, size_t ws_size,
                              hipStream_t stream) {
    const float* X    = (const float*)d_in[0];  // [128,512,512]
    const float* W    = (const float*)d_in[1];  // [512,512]
    const float* bias = (const float*)d_in[2];  // [512]
    float* out = (float*)d_out;                 // [128*512*512] spikes + [1] sum
    float* sum_slot = out + (size_t)M_TOT * N_DIM;

    if (ws_size >= WS_NEEDED) {
        unsigned short* Xb = (unsigned short*)d_ws;
        unsigned short* Wb = Xb + X_ELEMS;
        unsigned short* Cb = Wb + W_ELEMS;
        const int nconv = (int)((X_ELEMS / 8 + W_ELEMS / 8) / 256);  // 16512
        convert_bf16<<<nconv, 256, 0, stream>>>(X, W, Xb, Wb, sum_slot);
        gemm_fast<<<(M_TOT / BM) * (N_DIM / BN), 256, 0, stream>>>(Xb, Wb, bias, Cb);
        lif_scan<<<M_TOT / 256, 256, 0, stream>>>(Cb, out, sum_slot);
    } else {
        gemm_slow<<<(M_TOT / BM) * (N_DIM / BN), 256, 0, stream>>>(X, W, bias, out, sum_slot);
        lif_scan_f32<<<M_TOT / 256, 256, 0, stream>>>(out, sum_slot);
    }
}

// Round 9
// 274.708 us; speedup vs baseline: 1.1546x; 1.1546x over previous
//
#include <hip/hip_runtime.h>
#include <hip/hip_bf16.h>

// B=128, T=512, D_IN=512, D_OUT=512
// Fused: per (b, 128-d slice) block, loop 4 t-chunks in order:
//   bf16 MFMA GEMM tile -> LDS transpose (bf16, +bias) -> in-kernel LIF scan
// Spikes (f32) stream to d_out; spike-count summed exactly via int + atomicAdd.
#define M_TOT 65536
#define K_DIM 512
#define N_DIM 512
#define T_STEPS 512
#define BETA 0.95f

#define BM 128
#define BN 128
#define BK 64

typedef __attribute__((ext_vector_type(8))) short bf16x8;
typedef __attribute__((ext_vector_type(8))) unsigned short u16x8;
typedef __attribute__((ext_vector_type(4))) float f32x4;

#define X_ELEMS ((size_t)M_TOT * K_DIM)   // 33,554,432
#define W_ELEMS ((size_t)N_DIM * K_DIM)   // 262,144
#define WS_NEEDED ((X_ELEMS + W_ELEMS) * 2)

static __device__ __forceinline__ unsigned short f2bf(float f) {
    __hip_bfloat16 h = __float2bfloat16(f);   // v_cvt_pk_bf16_f32 (RNE)
    return __builtin_bit_cast(unsigned short, h);
}
static __device__ __forceinline__ float bf2f(unsigned short u) {
    return __builtin_bit_cast(float, (unsigned int)u << 16);
}

#define GLL(src, dst) __builtin_amdgcn_global_load_lds( \
    (const __attribute__((address_space(1))) unsigned int*)(const void*)(src), \
    (__attribute__((address_space(3))) unsigned int*)(void*)(dst), 16, 0, 0)

// ---------------- pass 1: f32 -> bf16 for X and W, zero the sum slot ----------
__global__ __launch_bounds__(256) void convert_bf16(
    const float* __restrict__ X, const float* __restrict__ W,
    unsigned short* __restrict__ Xb, unsigned short* __restrict__ Wb,
    float* __restrict__ sum_out)
{
    const size_t gid = (size_t)blockIdx.x * 256 + threadIdx.x;
    if (gid == 0) *sum_out = 0.0f;
    const size_t NXT = X_ELEMS / 8;
    if (gid < NXT) {
        const float4 v0 = *(const float4*)(X + gid * 8);
        const float4 v1 = *(const float4*)(X + gid * 8 + 4);
        u16x8 o;
        o[0] = f2bf(v0.x); o[1] = f2bf(v0.y); o[2] = f2bf(v0.z); o[3] = f2bf(v0.w);
        o[4] = f2bf(v1.x); o[5] = f2bf(v1.y); o[6] = f2bf(v1.z); o[7] = f2bf(v1.w);
        *(u16x8*)(Xb + gid * 8) = o;
    } else {
        const size_t g2 = gid - NXT;
        const float4 v0 = *(const float4*)(W + g2 * 8);
        const float4 v1 = *(const float4*)(W + g2 * 8 + 4);
        u16x8 o;
        o[0] = f2bf(v0.x); o[1] = f2bf(v0.y); o[2] = f2bf(v0.z); o[3] = f2bf(v0.w);
        o[4] = f2bf(v1.x); o[5] = f2bf(v1.y); o[6] = f2bf(v1.z); o[7] = f2bf(v1.w);
        *(u16x8*)(Wb + g2 * 8) = o;
    }
}

// ---------------- pass 2: fused GEMM + LIF ------------------------------------
// LDS map (ushort idx): [0,8192) Xs0 | [8192,16384) Ws0 | [16384,24576) Xs1 |
// [24576,32768) Ws1.  T (128x128 bf16 transpose buffer) ALIASES [16384,32768).
__global__ __launch_bounds__(256) void fused_gemm_lif(
    const unsigned short* __restrict__ Xb,  // [M_TOT][K_DIM] bf16
    const unsigned short* __restrict__ Wb,  // [N_DIM][K_DIM] bf16
    const float* __restrict__ bias,
    float* __restrict__ S,                  // [B][T][D] f32 spikes
    float* __restrict__ sum_out)
{
    __shared__ alignas(16) unsigned short lds[32768]; // 64 KB
    __shared__ int wsum[4];

    const int lin = blockIdx.x;             // 0..511 (512 % 8 == 0: bijective)
    const int swz = (lin & 7) * 64 + (lin >> 3);
    const int b   = swz >> 2;               // batch 0..127
    const int d0  = (swz & 3) * 128;        // output-column slice

    const int tid  = threadIdx.x;
    const int lane = tid & 63;
    const int wave = tid >> 6;
    const int wr = wave >> 1;
    const int wc = wave & 1;

    // staging geometry (verified r6/r7): instruction (wave,j) fills rows
    // wave*32+j*8..+7; HW dest = base + lane*16; source pre-swizzled
    const int srow = lane >> 3;
    const int scb  = (lane & 7) ^ (srow & 7);

    const unsigned short* wsrc[4];
    #pragma unroll
    for (int j = 0; j < 4; ++j)
        wsrc[j] = Wb + (size_t)(d0 + wave * 32 + j * 8 + srow) * K_DIM + scb * 8;

    const int frow = lane & 15;
    const int cblk = lane >> 4;

    float bv[4];
    #pragma unroll
    for (int n = 0; n < 4; ++n)
        bv[n] = bias[d0 + wc * 64 + n * 16 + frow];

    float mem = 0.0f;   // LIF state for this thread's neuron (persists over mt)
    int count = 0;

    for (int mt = 0; mt < 4; ++mt) {
        const int row0 = b * T_STEPS + mt * 128;   // global current-row base
        const unsigned short* xsrc[4];
        #pragma unroll
        for (int j = 0; j < 4; ++j)
            xsrc[j] = Xb + (size_t)(row0 + wave * 32 + j * 8 + srow) * K_DIM + scb * 8;

        // prologue: stage k=0 into buf0 (scan waves of prev mt issue late; safe)
        #pragma unroll
        for (int j = 0; j < 4; ++j) {
            GLL(xsrc[j], &lds[(wave * 32 + j * 8) * BK]);
            GLL(wsrc[j], &lds[8192 + (wave * 32 + j * 8) * BK]);
        }

        f32x4 acc[4][4] = {};

        #pragma unroll
        for (int k = 0; k < 8; ++k) {
            const int cur = k & 1;
            __syncthreads();   // drains vmcnt: stage(k) landed; prior reads of buf[cur^1] done
            if (k < 7) {
                const int nb = (cur ^ 1) * 16384;
                #pragma unroll
                for (int j = 0; j < 4; ++j) {
                    GLL(xsrc[j] + (k + 1) * BK, &lds[nb + (wave * 32 + j * 8) * BK]);
                    GLL(wsrc[j] + (k + 1) * BK, &lds[nb + 8192 + (wave * 32 + j * 8) * BK]);
                }
            }
            const int cb = cur * 16384;
            #pragma unroll
            for (int kh = 0; kh < 2; ++kh) {
                bf16x8 afr[4], bfr[4];
                #pragma unroll
                for (int m = 0; m < 4; ++m) {
                    int row = wr * 64 + m * 16 + frow;
                    int c = (kh * 4 + cblk) ^ (row & 7);
                    afr[m] = *(const bf16x8*)(&lds[cb + row * BK + c * 8]);
                }
                #pragma unroll
                for (int n = 0; n < 4; ++n) {
                    int row = wc * 64 + n * 16 + frow;
                    int c = (kh * 4 + cblk) ^ (row & 7);
                    bfr[n] = *(const bf16x8*)(&lds[cb + 8192 + row * BK + c * 8]);
                }
                #pragma unroll
                for (int m = 0; m < 4; ++m)
                    #pragma unroll
                    for (int n = 0; n < 4; ++n)
                        acc[m][n] = __builtin_amdgcn_mfma_f32_16x16x32_bf16(
                            afr[m], bfr[n], acc[m][n], 0, 0, 0);
            }
        }

        __syncthreads();   // ALL waves' MFMA reads of buf1 done before T overwrite

        // acc -> T[t][d] bf16 (+bias). Swizzle pd = d ^ ((t>>2 & 3)<<4):
        // write: 4 lane-groups (t+{0,4,8,12}) -> 4 distinct 16-blocks -> 32 banks.
        // read: fixed t, d=lane -> XOR-const permutation -> 32 banks. Both free.
        #pragma unroll
        for (int n = 0; n < 4; ++n) {
            const int d_ = wc * 64 + n * 16 + frow;
            #pragma unroll
            for (int m = 0; m < 4; ++m) {
                const int tb = wr * 64 + m * 16 + ((lane >> 4) << 2);
                #pragma unroll
                for (int r = 0; r < 4; ++r) {
                    const int t_ = tb + r;
                    lds[16384 + t_ * 128 + (d_ ^ (((t_ >> 2) & 3) << 4))] =
                        f2bf(acc[m][n][r] + bv[n]);
                }
            }
        }

        __syncthreads();

        // LIF scan: waves 0,1 own one neuron column each (d = tid), 128 t-steps.
        // Waves 2,3 fall through and prefetch next mt's k0 (overlap).
        if (tid < 128) {
            float* qb = S + (size_t)row0 * N_DIM + d0 + tid;
            for (int t2 = 0; t2 < 128; t2 += 8) {
                float v[8];
                #pragma unroll
                for (int j = 0; j < 8; ++j) {
                    const int tt = t2 + j;
                    v[j] = bf2f(lds[16384 + tt * 128 + (tid ^ (((tt >> 2) & 3) << 4))]);
                }
                #pragma unroll
                for (int j = 0; j < 8; ++j) {
                    mem = BETA * mem + v[j];
                    float spk = (mem > 1.0f) ? 1.0f : 0.0f;
                    mem -= spk;
                    __builtin_nontemporal_store(spk, qb + (size_t)(t2 + j) * N_DIM);
                    count += (int)spk;
                }
            }
        }
        // next mt's first __syncthreads orders scan reads before buf1 re-stage (k=1)
    }

    // exact spike-count reduction (waves 2,3 contribute 0)
    #pragma unroll
    for (int off = 32; off > 0; off >>= 1)
        count += __shfl_down(count, off);
    if ((tid & 63) == 0) wsum[tid >> 6] = count;
    __syncthreads();
    if (tid == 0)
        atomicAdd(sum_out, (float)(wsum[0] + wsum[1] + wsum[2] + wsum[3]));
}

// ---------------- fallback (ws too small): round-5/7 known-good path ---------
static __device__ __forceinline__ void stage_tiles(
    unsigned short (*__restrict__ Xs)[BK], unsigned short (*__restrict__ Ws)[BK],
    const float4* xr, const float4* wv, int sr0, int skg)
{
    #pragma unroll
    for (int i = 0; i < 8; ++i) {
        int r   = sr0 + i * 16;
        int kgs = skg ^ ((r & 7) << 3);
        ushort4 xb, wb;
        xb.x = f2bf(xr[i].x); xb.y = f2bf(xr[i].y); xb.z = f2bf(xr[i].z); xb.w = f2bf(xr[i].w);
        wb.x = f2bf(wv[i].x); wb.y = f2bf(wv[i].y); wb.z = f2bf(wv[i].z); wb.w = f2bf(wv[i].w);
        *(ushort4*)(&Xs[r][kgs]) = xb;
        *(ushort4*)(&Ws[r][kgs]) = wb;
    }
}

__global__ __launch_bounds__(256, 2) void gemm_slow(
    const float* __restrict__ X, const float* __restrict__ W,
    const float* __restrict__ bias, float* __restrict__ C,
    float* __restrict__ sum_out)
{
    __shared__ unsigned short Xs[2][BM][BK];
    __shared__ unsigned short Ws[2][BN][BK];

    const int lin  = blockIdx.x;
    const int swz  = (lin & 7) * 256 + (lin >> 3);
    const int mtile = swz >> 2;
    const int ntile = swz & 3;

    const int tid  = threadIdx.x;
    const int lane = tid & 63;
    const int wave = tid >> 6;
    const int wr = wave >> 1;
    const int wc = wave & 1;

    if (lin == 0 && tid == 0) *sum_out = 0.0f;

    const int row0 = mtile * BM;
    const int col0 = ntile * BN;

    f32x4 acc[4][4] = {};

    const int sr0 = tid >> 4;
    const int skg = (tid & 15) << 2;
    const float* xbase = X + (size_t)row0 * K_DIM + skg;
    const float* wbase = W + (size_t)col0 * K_DIM + skg;

    float4 xr[8], wv[8];
    #pragma unroll
    for (int i = 0; i < 8; ++i) {
        int r = sr0 + i * 16;
        xr[i] = *(const float4*)(xbase + (size_t)r * K_DIM);
        wv[i] = *(const float4*)(wbase + (size_t)r * K_DIM);
    }
    stage_tiles(Xs[0], Ws[0], xr, wv, sr0, skg);

    const int frow = lane & 15;
    const int cblk = lane >> 4;

    for (int t = 0; t < 8; ++t) {
        __syncthreads();
        if (t < 7) {
            const int k0n = (t + 1) * BK;
            #pragma unroll
            for (int i = 0; i < 8; ++i) {
                int r = sr0 + i * 16;
                xr[i] = *(const float4*)(xbase + (size_t)r * K_DIM + k0n);
                wv[i] = *(const float4*)(wbase + (size_t)r * K_DIM + k0n);
            }
        }
        unsigned short (*Xbuf)[BK] = Xs[t & 1];
        unsigned short (*Wbuf)[BK] = Ws[t & 1];
        #pragma unroll
        for (int kh = 0; kh < 2; ++kh) {
            bf16x8 afr[4], bfr[4];
            #pragma unroll
            for (int m = 0; m < 4; ++m) {
                int row = wr * 64 + m * 16 + frow;
                int c = (kh * 4 + cblk) ^ (row & 7);
                afr[m] = *(const bf16x8*)(&Xbuf[row][c * 8]);
            }
            #pragma unroll
            for (int n = 0; n < 4; ++n) {
                int row = wc * 64 + n * 16 + frow;
                int c = (kh * 4 + cblk) ^ (row & 7);
                bfr[n] = *(const bf16x8*)(&Wbuf[row][c * 8]);
            }
            #pragma unroll
            for (int m = 0; m < 4; ++m)
                #pragma unroll
                for (int n = 0; n < 4; ++n)
                    acc[m][n] = __builtin_amdgcn_mfma_f32_16x16x32_bf16(
                        afr[m], bfr[n], acc[m][n], 0, 0, 0);
        }
        if (t < 7)
            stage_tiles(Xs[(t + 1) & 1], Ws[(t + 1) & 1], xr, wv, sr0, skg);
    }

    const int crow_base = (lane >> 4) * 4;
    const int ccol = lane & 15;
    #pragma unroll
    for (int n = 0; n < 4; ++n) {
        int col = col0 + wc * 64 + n * 16 + ccol;
        float bvv = bias[col];
        #pragma unroll
        for (int m = 0; m < 4; ++m) {
            int rowb = row0 + wr * 64 + m * 16 + crow_base;
            #pragma unroll
            for (int r = 0; r < 4; ++r) {
                C[(size_t)(rowb + r) * N_DIM + col] = acc[m][n][r] + bvv;
            }
        }
    }
}

__global__ __launch_bounds__(256) void lif_scan_f32(
    float* __restrict__ C, float* __restrict__ sum_out)
{
    const int idx = blockIdx.x * 256 + threadIdx.x;
    float* p = C + (size_t)(idx >> 9) * (T_STEPS * N_DIM) + (idx & 511);
    float mem = 0.0f;
    int count = 0;
    for (int t = 0; t < T_STEPS; t += 8) {
        float cur[8];
        #pragma unroll
        for (int j = 0; j < 8; ++j) cur[j] = p[(size_t)(t + j) * N_DIM];
        #pragma unroll
        for (int j = 0; j < 8; ++j) {
            mem = BETA * mem + cur[j];
            float spk = (mem > 1.0f) ? 1.0f : 0.0f;
            mem -= spk;
            p[(size_t)(t + j) * N_DIM] = spk;
            count += (int)spk;
        }
    }
    #pragma unroll
    for (int off = 32; off > 0; off >>= 1) count += __shfl_down(count, off);
    __shared__ int wsum[4];
    if ((threadIdx.x & 63) == 0) wsum[threadIdx.x >> 6] = count;
    __syncthreads();
    if (threadIdx.x == 0)
        atomicAdd(sum_out, (float)(wsum[0] + wsum[1] + wsum[2] + wsum[3]));
}

extern "C" void kernel_launch(void* const* d_in, const int* in_sizes, int n_in,
                              void* d_out, int out_size, void* d_ws, size_t ws_size,
                              hipStream_t stream) {
    const float* X    = (const float*)d_in[0];  // [128,512,512]
    const float* W    = (const float*)d_in[1];  // [512,512]
    const float* bias = (const float*)d_in[2];  // [512]
    float* out = (float*)d_out;                 // [128*512*512] spikes + [1] sum
    float* sum_slot = out + (size_t)M_TOT * N_DIM;

    if (ws_size >= WS_NEEDED) {
        unsigned short* Xb = (unsigned short*)d_ws;
        unsigned short* Wb = Xb + X_ELEMS;
        const int nconv = (int)((X_ELEMS / 8 + W_ELEMS / 8) / 256);  // 16512
        convert_bf16<<<nconv, 256, 0, stream>>>(X, W, Xb, Wb, sum_slot);
        fused_gemm_lif<<<512, 256, 0, stream>>>(Xb, Wb, bias, out, sum_slot);
    } else {
        gemm_slow<<<(M_TOT / BM) * (N_DIM / BN), 256, 0, stream>>>(X, W, bias, out, sum_slot);
        lif_scan_f32<<<M_TOT / 256, 256, 0, stream>>>(out, sum_slot);
    }
}